// Round 9
// baseline (114.198 us; speedup 1.0000x reference)
//
#include <hip/hip_runtime.h>
#include <hip/hip_bf16.h>

// R9: row_engine was the top dispatch (46.7 us, 3% HBM, 0.3% MFMA) — R8's
// VGPR_Count=80 proves the allocator serialized the 16-70 HBM loads per wave
// into load->wait->exp->load chains (~70 x ~1000 cyc = the whole 46 us).
// With 256 blocks = 1 block/CU, up to 512 VGPR/wave are free: declare
// __launch_bounds__(256, 1) and restructure to explicit load-batch-then-
// compute (x-type: one 16-load window; pair-type: ii/jj -> {noise || gather}
// -> compute, ~3 windows). Arithmetic bitwise identical to R8 (absmax
// 0.03125). pairwise/finalize verbatim from R8.

typedef short bf16x8 __attribute__((ext_vector_type(8)));
typedef float f32x4 __attribute__((ext_vector_type(4)));

__device__ __forceinline__ float wave_sum(float v) {
#pragma unroll
  for (int off = 32; off; off >>= 1) v += __shfl_xor(v, off);
  return v;
}

__device__ __forceinline__ unsigned short f2bf(float x) {  // RNE, finite inputs
  union { float f; unsigned u; } v; v.f = x;
  return (unsigned short)((v.u + 0x7fffu + ((v.u >> 16) & 1u)) >> 16);
}
__device__ __forceinline__ float bf2f(unsigned short h) {
  union { float f; unsigned u; } v; v.u = ((unsigned)h) << 16;
  return v.f;
}

// Load one gumbel batch: 16 float4 (L,U) into registers, no intervening math.
// p pre-offset to (row, part*8); q covers (ks=q>>1, h=q&1) -> ks*32 + h*4.
__device__ __forceinline__ void gs_load(const float* __restrict__ lgp,
                                        const float* __restrict__ nzp,
                                        float4 L[8], float4 U[8]) {
#pragma unroll
  for (int q = 0; q < 8; ++q) {
    L[q] = *(const float4*)(lgp + (q >> 1) * 32 + (q & 1) * 4);
    U[q] = *(const float4*)(nzp + (q >> 1) * 32 + (q & 1) * 4);
  }
}

// Compute phase: softmax from registers -> bf16 A-fragments -> 16 MFMAs.
// Same op order as R8's gumbel_mfma (e[q*4+j] == e[ks*8+h*4+j]).
__device__ __forceinline__ void gs_compute(const float4 L[8], const float4 U[8],
                                           const bf16x8 Bf[4][4], f32x4 acc[4]) {
  float e[32];
  float ps = 0.0f;
#pragma unroll
  for (int q = 0; q < 8; ++q) {
    float lv[4] = {L[q].x, L[q].y, L[q].z, L[q].w};
    float uv[4] = {U[q].x, U[q].y, U[q].z, U[q].w};
#pragma unroll
    for (int j = 0; j < 4; ++j) {
      float g = -__logf(-__logf(uv[j] + 1e-9f) + 1e-9f);
      float ev = __expf(lv[j] + g);
      e[q * 4 + j] = ev;
      ps += ev;
    }
  }
  ps += __shfl_xor(ps, 16);
  ps += __shfl_xor(ps, 32);
  float inv = __builtin_amdgcn_rcpf(ps);
#pragma unroll
  for (int ks = 0; ks < 4; ++ks) {
    union { bf16x8 v; unsigned short s[8]; } pk;
#pragma unroll
    for (int j = 0; j < 8; ++j) pk.s[j] = f2bf(e[ks * 8 + j] * inv);
#pragma unroll
    for (int nt = 0; nt < 4; ++nt)
      acc[nt] = __builtin_amdgcn_mfma_f32_16x16x32_bf16(pk.v, Bf[nt][ks], acc[nt], 0, 0, 0);
  }
}

__device__ __forceinline__ void load_Bf(const float* __restrict__ topic_w,
                                        int r, int part, bf16x8 Bf[4][4]) {
  // lane (r,part), step ks: B[k = ks*32+part*8+j][n = nt*16+r] = W[n][k].
#pragma unroll
  for (int nt = 0; nt < 4; ++nt) {
    const float* wp = topic_w + (nt * 16 + r) * 128 + part * 8;
#pragma unroll
    for (int ks = 0; ks < 4; ++ks) {
      float4 w0 = *(const float4*)(wp + ks * 32);
      float4 w1 = *(const float4*)(wp + ks * 32 + 4);
      union { bf16x8 v; unsigned short s[8]; } pk;
      pk.s[0] = f2bf(w0.x); pk.s[1] = f2bf(w0.y); pk.s[2] = f2bf(w0.z); pk.s[3] = f2bf(w0.w);
      pk.s[4] = f2bf(w1.x); pk.s[5] = f2bf(w1.y); pk.s[6] = f2bf(w1.z); pk.s[7] = f2bf(w1.w);
      Bf[nt][ks] = pk.v;
    }
  }
}

// grid 256 x 256 threads, 1 block/CU. wid even -> x-type, wid odd -> pair.
__global__ __launch_bounds__(256, 1) void row_engine(
    const float* __restrict__ logits, const float* __restrict__ noise_f,
    const float* __restrict__ noise_i, const float* __restrict__ noise_j,
    const float* __restrict__ topic_w, const float* __restrict__ tb,
    const int* __restrict__ ii, const int* __restrict__ jj,
    unsigned short* __restrict__ xb, float* __restrict__ sq,
    float* __restrict__ denomS) {
  int w = threadIdx.x >> 6, lane = threadIdx.x & 63;
  int r = lane & 15, part = lane >> 4;
  int wid = blockIdx.x * 4 + w;
  int grp = wid >> 1;

  if ((wid & 1) == 0) {
    // x-type: rows g16..g16+15. One load window, then compute.
    int g16 = grp * 16;
    float4 L[8], U[8];
    gs_load(logits + (g16 + r) * 128 + part * 8,
            noise_f + (g16 + r) * 128 + part * 8, L, U);
    bf16x8 Bf[4][4];
    load_Bf(topic_w, r, part, Bf);
    float tbv[4];
#pragma unroll
    for (int nt = 0; nt < 4; ++nt) tbv[nt] = tb[nt * 16 + r];
    f32x4 acc[4] = {};
    gs_compute(L, U, Bf, acc);
    // C-layout: row m = part*4+g, col n = nt*16+r.
    float sqp[4] = {0.f, 0.f, 0.f, 0.f};
#pragma unroll
    for (int nt = 0; nt < 4; ++nt)
#pragma unroll
      for (int g = 0; g < 4; ++g) {
        unsigned short hb = f2bf(acc[nt][g] + tbv[nt]);
        xb[(g16 + part * 4 + g) * 64 + nt * 16 + r] = hb;
        float xr = bf2f(hb);  // rounded value -> sq consistent with Gram dot
        sqp[g] += xr * xr;
      }
#pragma unroll
    for (int m = 1; m < 16; m <<= 1)
#pragma unroll
      for (int g = 0; g < 4; ++g) sqp[g] += __shfl_xor(sqp[g], m);
    if (r == 0) {
#pragma unroll
      for (int g = 0; g < 4; ++g) sq[g16 + part * 4 + g] = sqp[g];
    }
  } else {
    // pair-type: batch elems b0..b0+15. Windows: ii/jj -> {Ui,Uj || Li,Lj}.
    int b0 = grp * 16;
    int rowi = ii[b0 + r], rowj = jj[b0 + r];  // oldest loads; gather dep
    float4 Li[8], Ui[8], Lj[8], Uj[8];
    // noise loads are independent of rowi/rowj -> stay in flight over the wait
    gs_load(logits + rowi * 128 + part * 8,
            noise_i + (b0 + r) * 128 + part * 8, Li, Ui);
    gs_load(logits + rowj * 128 + part * 8,
            noise_j + (b0 + r) * 128 + part * 8, Lj, Uj);
    bf16x8 Bf[4][4];
    load_Bf(topic_w, r, part, Bf);
    f32x4 ai[4] = {}, aj[4] = {};
    gs_compute(Li, Ui, Bf, ai);
    gs_compute(Lj, Uj, Bf, aj);
    float dp[4] = {0.f, 0.f, 0.f, 0.f};
#pragma unroll
    for (int nt = 0; nt < 4; ++nt)
#pragma unroll
      for (int g = 0; g < 4; ++g) {
        float d = ai[nt][g] - aj[nt][g];
        dp[g] += d * d;
      }
#pragma unroll
    for (int m = 1; m < 16; m <<= 1)
#pragma unroll
      for (int g = 0; g < 4; ++g) dp[g] += __shfl_xor(dp[g], m);
    if (r == 0) {
#pragma unroll
      for (int g = 0; g < 4; ++g) denomS[b0 + part * 4 + g] = 64.0f + dp[g];
    }
  }
}

// Fat-block triangular pairwise, software-pipelined: 544 blocks, block =
// (row-band bi, chunk of <=4 column tiles). A-frags + m1 loaded once; B/nsq
// for tile bj+1 prefetched during tile bj's MFMA+epilogue (double buffer).
#define NPAIR_BLOCKS 544
__global__ __launch_bounds__(256) void pairwise(const unsigned short* __restrict__ xbp,
                                                const float* __restrict__ sq,
                                                float* __restrict__ partial) {
  __shared__ float red[4];
  int w = threadIdx.x >> 6, lane = threadIdx.x & 63;
  // decode blockIdx -> (bi, cj0): bi row-band, chunks of 4 over bj in [bi,63]
  int b = blockIdx.x, bi = 0, nch = 16;
  while (b >= nch) { b -= nch; ++bi; nch = (64 - bi + 3) >> 2; }
  int cj0 = bi + (b << 2);
  int wr = w >> 1, wc = w & 1;
  int R = bi * 128 + wr * 64;
  int r0 = lane & 15, kq = lane >> 4;

  bf16x8 A[4][2];
#pragma unroll
  for (int a = 0; a < 4; ++a)
#pragma unroll
    for (int s = 0; s < 2; ++s)
      A[a][s] = *(const bf16x8*)(xbp + (R + a * 16 + r0) * 64 + s * 32 + kq * 8);
  float m1[4][4];
#pragma unroll
  for (int a = 0; a < 4; ++a)
#pragma unroll
    for (int g = 0; g < 4; ++g) m1[a][g] = 1.0f + sq[R + a * 16 + kq * 4 + g];

  float local = 0.0f;
  int bjEnd = min(cj0 + 4, 64);
  int bj = cj0;
  if (cj0 == bi && wr > wc) ++bj;  // lower-left wave of the diag tile: skip it
  if (bj < bjEnd) {
    // prologue: load tile bj
    bf16x8 Bc[4][2];
    float nsqc[4];
    {
      int C = bj * 128 + wc * 64;
#pragma unroll
      for (int a = 0; a < 4; ++a)
#pragma unroll
        for (int s = 0; s < 2; ++s)
          Bc[a][s] = *(const bf16x8*)(xbp + (C + a * 16 + r0) * 64 + s * 32 + kq * 8);
#pragma unroll
      for (int q = 0; q < 4; ++q) nsqc[q] = sq[C + q * 16 + r0];
    }
    for (; bj < bjEnd; ++bj) {
      bool hasNext = (bj + 1) < bjEnd;
      bf16x8 Bn[4][2];
      float nsqn[4];
      if (hasNext) {  // issue next tile's loads before this tile's compute
        int Cn = (bj + 1) * 128 + wc * 64;
#pragma unroll
        for (int a = 0; a < 4; ++a)
#pragma unroll
          for (int s = 0; s < 2; ++s)
            Bn[a][s] = *(const bf16x8*)(xbp + (Cn + a * 16 + r0) * 64 + s * 32 + kq * 8);
#pragma unroll
        for (int q = 0; q < 4; ++q) nsqn[q] = sq[Cn + q * 16 + r0];
      }

      f32x4 acc[4][4] = {};
#pragma unroll
      for (int a = 0; a < 4; ++a)
#pragma unroll
        for (int q = 0; q < 4; ++q) {
          acc[a][q] = __builtin_amdgcn_mfma_f32_16x16x32_bf16(A[a][0], Bc[q][0], acc[a][q], 0, 0, 0);
          acc[a][q] = __builtin_amdgcn_mfma_f32_16x16x32_bf16(A[a][1], Bc[q][1], acc[a][q], 0, 0, 0);
        }

      if (bj == bi && wr == wc) {  // tile straddling the diagonal: r<c only
#pragma unroll
        for (int a = 0; a < 4; ++a)
#pragma unroll
          for (int q = 0; q < 4; ++q)
#pragma unroll
            for (int g = 0; g < 4; ++g) {
              float d = fmaf(-2.0f, acc[a][q][g], m1[a][g] + nsqc[q]);
              int rl = a * 16 + kq * 4 + g, cl = q * 16 + r0;
              local += (rl < cl) ? __builtin_amdgcn_rcpf(d) : 0.0f;
            }
      } else {
#pragma unroll
        for (int a = 0; a < 4; ++a)
#pragma unroll
          for (int q = 0; q < 4; ++q)
#pragma unroll
            for (int g = 0; g < 4; ++g) {
              float d = fmaf(-2.0f, acc[a][q][g], m1[a][g] + nsqc[q]);
              local += __builtin_amdgcn_rcpf(d);
            }
      }

      if (hasNext) {
#pragma unroll
        for (int a = 0; a < 4; ++a)
#pragma unroll
          for (int s = 0; s < 2; ++s) Bc[a][s] = Bn[a][s];
#pragma unroll
        for (int q = 0; q < 4; ++q) nsqc[q] = nsqn[q];
      }
    }
  }
  local = wave_sum(local);
  if (lane == 0) red[w] = local;
  __syncthreads();
  if (threadIdx.x == 0) partial[blockIdx.x] = red[0] + red[1] + red[2] + red[3];
}

// part = 2 * sum_{m<n} rcp = (ref's full sum incl. diagonal) - 8192 exactly.
__global__ __launch_bounds__(256) void finalize(const float* __restrict__ pij,
                                                const float* __restrict__ denomS,
                                                const float* __restrict__ partial,
                                                float* __restrict__ out) {
  __shared__ float red[4];
  int tid = threadIdx.x, w = tid >> 6, lane = tid & 63;
  float ps = 0.0f;
  for (int k = tid; k < NPAIR_BLOCKS; k += 256) ps += partial[k];
  ps = wave_sum(ps);
  if (lane == 0) red[w] = ps;
  __syncthreads();
  float part = 2.0f * (red[0] + red[1] + red[2] + red[3]);
  int b = blockIdx.x * 256 + tid;
  float p = pij[b];
  out[b] = p * (__logf(p) + __logf(denomS[b]) + __logf(part));
}

extern "C" void kernel_launch(void* const* d_in, const int* in_sizes, int n_in,
                              void* d_out, int out_size, void* d_ws, size_t ws_size,
                              hipStream_t stream) {
  const float* pij     = (const float*)d_in[0];
  const float* noise_f = (const float*)d_in[1];
  const float* noise_i = (const float*)d_in[2];
  const float* noise_j = (const float*)d_in[3];
  const float* logits  = (const float*)d_in[4];
  const float* topic_w = (const float*)d_in[5];
  const float* tb      = (const float*)d_in[6];
  const int*   ii      = (const int*)d_in[7];
  const int*   jj      = (const int*)d_in[8];
  float* out = (float*)d_out;

  char* ws = (char*)d_ws;
  float* partial     = (float*)ws;                               // 544 f32
  unsigned short* xb = (unsigned short*)(ws + 8192);             // 8192*64 bf16 = 1 MB
  float* sq          = (float*)(ws + 8192 + 1048576);            // 8192 f32
  float* denomS      = (float*)(ws + 8192 + 1048576 + 32768);    // 8192 f32

  row_engine<<<256, 256, 0, stream>>>(logits, noise_f, noise_i, noise_j,
                                      topic_w, tb, ii, jj, xb, sq, denomS);
  pairwise<<<NPAIR_BLOCKS, 256, 0, stream>>>(xb, sq, partial);
  finalize<<<32, 256, 0, stream>>>(pij, denomS, partial, out);
}

// Round 10
// 113.874 us; speedup vs baseline: 1.0029x; 1.0029x over previous
//
#include <hip/hip_runtime.h>
#include <hip/hip_bf16.h>

// R10: row_engine rebuilt around __builtin_amdgcn_global_load_lds (width=16).
// R8/R9 evidence: the compiler serializes register-target loads against the
// transcendental chain regardless of source structure (VGPR=80 in R8; R9's
// explicit batching changed nothing) -> ~40 us of exposed latency at 4
// waves/CU. global_load_lds ops have no SSA result, so they CANNOT be sunk:
// all ~40 staging loads issue back-to-back, drained once by __syncthreads
// (compiler emits s_waitcnt vmcnt(0) before s_barrier — m97 pattern).
// LDS image is row-major [rows][128] f32 (lane l: row=2t+(l>>5), col4=l&31,
// HW dest = base + l*16 -> contiguous). Compute math bit-identical to R8
// (absmax 0.03125). pairwise/finalize verbatim from R8.

typedef short bf16x8 __attribute__((ext_vector_type(8)));
typedef float f32x4 __attribute__((ext_vector_type(4)));

__device__ __forceinline__ float wave_sum(float v) {
#pragma unroll
  for (int off = 32; off; off >>= 1) v += __shfl_xor(v, off);
  return v;
}

__device__ __forceinline__ unsigned short f2bf(float x) {  // RNE, finite inputs
  union { float f; unsigned u; } v; v.f = x;
  return (unsigned short)((v.u + 0x7fffu + ((v.u >> 16) & 1u)) >> 16);
}
__device__ __forceinline__ float bf2f(unsigned short h) {
  union { float f; unsigned u; } v; v.u = ((unsigned)h) << 16;
  return v.f;
}

// Async global->LDS, 16 B/lane. LDS dest is wave-uniform base + lane*16.
__device__ __forceinline__ void ld_lds16(const float* g, float* l) {
  __builtin_amdgcn_global_load_lds(
      (const __attribute__((address_space(1))) void*)g,
      (__attribute__((address_space(3))) void*)l, 16, 0, 0);
}

// Softmax+MFMA from a staged LDS image. Lb/Ub: [16 rows][128 cols] f32,
// stride 128 floats. Same op order as R8's gumbel_mfma -> identical bits.
__device__ __forceinline__ void gs_compute_lds(const float* Lb, const float* Ub,
                                               const bf16x8 Bf[4][4],
                                               int r, int part, f32x4 acc[4]) {
  float e[32];
  float ps = 0.0f;
#pragma unroll
  for (int q = 0; q < 8; ++q) {
    int off = r * 128 + (q >> 1) * 32 + part * 8 + (q & 1) * 4;
    float4 L = *(const float4*)(Lb + off);
    float4 U = *(const float4*)(Ub + off);
    float lv[4] = {L.x, L.y, L.z, L.w};
    float uv[4] = {U.x, U.y, U.z, U.w};
#pragma unroll
    for (int j = 0; j < 4; ++j) {
      float g = -__logf(-__logf(uv[j] + 1e-9f) + 1e-9f);
      float ev = __expf(lv[j] + g);
      e[q * 4 + j] = ev;
      ps += ev;
    }
  }
  ps += __shfl_xor(ps, 16);
  ps += __shfl_xor(ps, 32);
  float inv = __builtin_amdgcn_rcpf(ps);
#pragma unroll
  for (int ks = 0; ks < 4; ++ks) {
    union { bf16x8 v; unsigned short s[8]; } pk;
#pragma unroll
    for (int j = 0; j < 8; ++j) pk.s[j] = f2bf(e[ks * 8 + j] * inv);
#pragma unroll
    for (int nt = 0; nt < 4; ++nt)
      acc[nt] = __builtin_amdgcn_mfma_f32_16x16x32_bf16(pk.v, Bf[nt][ks], acc[nt], 0, 0, 0);
  }
}

// grid 256 x 256 threads (1 block/CU by LDS). w even -> x-type, w odd -> pair.
// LDS: W image [64][128] f32 (32 KB, staged cooperatively) + per-wave input
// regions (x: L,U = 16 KB; pair: Li,Ui,Lj,Uj = 32 KB) = 128 KB.
__global__ __launch_bounds__(256) void row_engine(
    const float* __restrict__ logits, const float* __restrict__ noise_f,
    const float* __restrict__ noise_i, const float* __restrict__ noise_j,
    const float* __restrict__ topic_w, const float* __restrict__ tb,
    const int* __restrict__ ii, const int* __restrict__ jj,
    unsigned short* __restrict__ xb, float* __restrict__ sq,
    float* __restrict__ denomS) {
  __shared__ __align__(16) float sh[32768];  // 128 KB
  int w = threadIdx.x >> 6, lane = threadIdx.x & 63;
  int r = lane & 15, part = lane >> 4;
  int wid = blockIdx.x * 4 + w;
  int grp = wid >> 1;
  int lsub = lane & 31;   // col4 index within a 512 B row
  int rhalf = lane >> 5;  // which of the 2 rows this lane covers

  // ---- stage W: wave w covers rows 16w..16w+15 (8 x 1 KB instrs) ----
#pragma unroll
  for (int t2 = 0; t2 < 8; ++t2) {
    int t = w * 8 + t2;
    ld_lds16(topic_w + (2 * t + rhalf) * 128 + lsub * 4, &sh[t * 256]);
  }

  // per-wave input region (floats): x-waves 4096, pair-waves 8192
  float* reg = &sh[8192 + (w >> 1) * 12288 + (w & 1) * 4096];

  if ((w & 1) == 0) {
    int g16 = grp * 16;
#pragma unroll
    for (int t = 0; t < 8; ++t) {
      int row = g16 + 2 * t + rhalf;
      ld_lds16(logits + row * 128 + lsub * 4, reg + t * 256);           // L
      ld_lds16(noise_f + row * 128 + lsub * 4, reg + 2048 + t * 256);   // U
    }
  } else {
    int b0 = grp * 16;
    int rowiv = ii[b0 + r], rowjv = jj[b0 + r];  // gather indices (lanes 0-15 mod 16)
    // noise staging is independent of the indices -> issues over their latency
#pragma unroll
    for (int t = 0; t < 8; ++t) {
      int brow = b0 + 2 * t + rhalf;
      ld_lds16(noise_i + brow * 128 + lsub * 4, reg + 2048 + t * 256);  // Ui
      ld_lds16(noise_j + brow * 128 + lsub * 4, reg + 6144 + t * 256);  // Uj
    }
#pragma unroll
    for (int t = 0; t < 8; ++t) {
      int ri = __shfl(rowiv, 2 * t + rhalf);
      int rj = __shfl(rowjv, 2 * t + rhalf);
      ld_lds16(logits + ri * 128 + lsub * 4, reg + t * 256);            // Li
      ld_lds16(logits + rj * 128 + lsub * 4, reg + 4096 + t * 256);     // Lj
    }
  }

  __syncthreads();  // vmcnt(0) drain before s_barrier: all staging lands

  // ---- Bf from the LDS W image: B[k=ks*32+part*8+j][n=nt*16+r] ----
  bf16x8 Bf[4][4];
#pragma unroll
  for (int nt = 0; nt < 4; ++nt) {
    const float* wp = &sh[(nt * 16 + r) * 128 + part * 8];
#pragma unroll
    for (int ks = 0; ks < 4; ++ks) {
      float4 w0 = *(const float4*)(wp + ks * 32);
      float4 w1 = *(const float4*)(wp + ks * 32 + 4);
      union { bf16x8 v; unsigned short s[8]; } pk;
      pk.s[0] = f2bf(w0.x); pk.s[1] = f2bf(w0.y); pk.s[2] = f2bf(w0.z); pk.s[3] = f2bf(w0.w);
      pk.s[4] = f2bf(w1.x); pk.s[5] = f2bf(w1.y); pk.s[6] = f2bf(w1.z); pk.s[7] = f2bf(w1.w);
      Bf[nt][ks] = pk.v;
    }
  }

  if ((w & 1) == 0) {
    // x-type: rows g16..g16+15. C-layout: row m = part*4+g, col n = nt*16+r.
    int g16 = grp * 16;
    float tbv[4];
#pragma unroll
    for (int nt = 0; nt < 4; ++nt) tbv[nt] = tb[nt * 16 + r];
    f32x4 acc[4] = {};
    gs_compute_lds(reg, reg + 2048, Bf, r, part, acc);
    float sqp[4] = {0.f, 0.f, 0.f, 0.f};
#pragma unroll
    for (int nt = 0; nt < 4; ++nt)
#pragma unroll
      for (int g = 0; g < 4; ++g) {
        unsigned short hb = f2bf(acc[nt][g] + tbv[nt]);
        xb[(g16 + part * 4 + g) * 64 + nt * 16 + r] = hb;
        float xr = bf2f(hb);  // rounded value -> sq consistent with Gram dot
        sqp[g] += xr * xr;
      }
#pragma unroll
    for (int m = 1; m < 16; m <<= 1)
#pragma unroll
      for (int g = 0; g < 4; ++g) sqp[g] += __shfl_xor(sqp[g], m);
    if (r == 0) {
#pragma unroll
      for (int g = 0; g < 4; ++g) sq[g16 + part * 4 + g] = sqp[g];
    }
  } else {
    // pair-type: denom = 64 + ||xi-xj||^2 (bias cancels in the difference).
    int b0 = grp * 16;
    f32x4 ai[4] = {}, aj[4] = {};
    gs_compute_lds(reg, reg + 2048, Bf, r, part, ai);
    gs_compute_lds(reg + 4096, reg + 6144, Bf, r, part, aj);
    float dp[4] = {0.f, 0.f, 0.f, 0.f};
#pragma unroll
    for (int nt = 0; nt < 4; ++nt)
#pragma unroll
      for (int g = 0; g < 4; ++g) {
        float d = ai[nt][g] - aj[nt][g];
        dp[g] += d * d;
      }
#pragma unroll
    for (int m = 1; m < 16; m <<= 1)
#pragma unroll
      for (int g = 0; g < 4; ++g) dp[g] += __shfl_xor(dp[g], m);
    if (r == 0) {
#pragma unroll
      for (int g = 0; g < 4; ++g) denomS[b0 + part * 4 + g] = 64.0f + dp[g];
    }
  }
}

// Fat-block triangular pairwise, software-pipelined: 544 blocks, block =
// (row-band bi, chunk of <=4 column tiles). A-frags + m1 loaded once; B/nsq
// for tile bj+1 prefetched during tile bj's MFMA+epilogue (double buffer).
#define NPAIR_BLOCKS 544
__global__ __launch_bounds__(256) void pairwise(const unsigned short* __restrict__ xbp,
                                                const float* __restrict__ sq,
                                                float* __restrict__ partial) {
  __shared__ float red[4];
  int w = threadIdx.x >> 6, lane = threadIdx.x & 63;
  // decode blockIdx -> (bi, cj0): bi row-band, chunks of 4 over bj in [bi,63]
  int b = blockIdx.x, bi = 0, nch = 16;
  while (b >= nch) { b -= nch; ++bi; nch = (64 - bi + 3) >> 2; }
  int cj0 = bi + (b << 2);
  int wr = w >> 1, wc = w & 1;
  int R = bi * 128 + wr * 64;
  int r0 = lane & 15, kq = lane >> 4;

  bf16x8 A[4][2];
#pragma unroll
  for (int a = 0; a < 4; ++a)
#pragma unroll
    for (int s = 0; s < 2; ++s)
      A[a][s] = *(const bf16x8*)(xbp + (R + a * 16 + r0) * 64 + s * 32 + kq * 8);
  float m1[4][4];
#pragma unroll
  for (int a = 0; a < 4; ++a)
#pragma unroll
    for (int g = 0; g < 4; ++g) m1[a][g] = 1.0f + sq[R + a * 16 + kq * 4 + g];

  float local = 0.0f;
  int bjEnd = min(cj0 + 4, 64);
  int bj = cj0;
  if (cj0 == bi && wr > wc) ++bj;  // lower-left wave of the diag tile: skip it
  if (bj < bjEnd) {
    bf16x8 Bc[4][2];
    float nsqc[4];
    {
      int C = bj * 128 + wc * 64;
#pragma unroll
      for (int a = 0; a < 4; ++a)
#pragma unroll
        for (int s = 0; s < 2; ++s)
          Bc[a][s] = *(const bf16x8*)(xbp + (C + a * 16 + r0) * 64 + s * 32 + kq * 8);
#pragma unroll
      for (int q = 0; q < 4; ++q) nsqc[q] = sq[C + q * 16 + r0];
    }
    for (; bj < bjEnd; ++bj) {
      bool hasNext = (bj + 1) < bjEnd;
      bf16x8 Bn[4][2];
      float nsqn[4];
      if (hasNext) {  // issue next tile's loads before this tile's compute
        int Cn = (bj + 1) * 128 + wc * 64;
#pragma unroll
        for (int a = 0; a < 4; ++a)
#pragma unroll
          for (int s = 0; s < 2; ++s)
            Bn[a][s] = *(const bf16x8*)(xbp + (Cn + a * 16 + r0) * 64 + s * 32 + kq * 8);
#pragma unroll
        for (int q = 0; q < 4; ++q) nsqn[q] = sq[Cn + q * 16 + r0];
      }

      f32x4 acc[4][4] = {};
#pragma unroll
      for (int a = 0; a < 4; ++a)
#pragma unroll
        for (int q = 0; q < 4; ++q) {
          acc[a][q] = __builtin_amdgcn_mfma_f32_16x16x32_bf16(A[a][0], Bc[q][0], acc[a][q], 0, 0, 0);
          acc[a][q] = __builtin_amdgcn_mfma_f32_16x16x32_bf16(A[a][1], Bc[q][1], acc[a][q], 0, 0, 0);
        }

      if (bj == bi && wr == wc) {  // tile straddling the diagonal: r<c only
#pragma unroll
        for (int a = 0; a < 4; ++a)
#pragma unroll
          for (int q = 0; q < 4; ++q)
#pragma unroll
            for (int g = 0; g < 4; ++g) {
              float d = fmaf(-2.0f, acc[a][q][g], m1[a][g] + nsqc[q]);
              int rl = a * 16 + kq * 4 + g, cl = q * 16 + r0;
              local += (rl < cl) ? __builtin_amdgcn_rcpf(d) : 0.0f;
            }
      } else {
#pragma unroll
        for (int a = 0; a < 4; ++a)
#pragma unroll
          for (int q = 0; q < 4; ++q)
#pragma unroll
            for (int g = 0; g < 4; ++g) {
              float d = fmaf(-2.0f, acc[a][q][g], m1[a][g] + nsqc[q]);
              local += __builtin_amdgcn_rcpf(d);
            }
      }

      if (hasNext) {
#pragma unroll
        for (int a = 0; a < 4; ++a)
#pragma unroll
          for (int s = 0; s < 2; ++s) Bc[a][s] = Bn[a][s];
#pragma unroll
        for (int q = 0; q < 4; ++q) nsqc[q] = nsqn[q];
      }
    }
  }
  local = wave_sum(local);
  if (lane == 0) red[w] = local;
  __syncthreads();
  if (threadIdx.x == 0) partial[blockIdx.x] = red[0] + red[1] + red[2] + red[3];
}

// part = 2 * sum_{m<n} rcp = (ref's full sum incl. diagonal) - 8192 exactly.
__global__ __launch_bounds__(256) void finalize(const float* __restrict__ pij,
                                                const float* __restrict__ denomS,
                                                const float* __restrict__ partial,
                                                float* __restrict__ out) {
  __shared__ float red[4];
  int tid = threadIdx.x, w = tid >> 6, lane = tid & 63;
  float ps = 0.0f;
  for (int k = tid; k < NPAIR_BLOCKS; k += 256) ps += partial[k];
  ps = wave_sum(ps);
  if (lane == 0) red[w] = ps;
  __syncthreads();
  float part = 2.0f * (red[0] + red[1] + red[2] + red[3]);
  int b = blockIdx.x * 256 + tid;
  float p = pij[b];
  out[b] = p * (__logf(p) + __logf(denomS[b]) + __logf(part));
}

extern "C" void kernel_launch(void* const* d_in, const int* in_sizes, int n_in,
                              void* d_out, int out_size, void* d_ws, size_t ws_size,
                              hipStream_t stream) {
  const float* pij     = (const float*)d_in[0];
  const float* noise_f = (const float*)d_in[1];
  const float* noise_i = (const float*)d_in[2];
  const float* noise_j = (const float*)d_in[3];
  const float* logits  = (const float*)d_in[4];
  const float* topic_w = (const float*)d_in[5];
  const float* tb      = (const float*)d_in[6];
  const int*   ii      = (const int*)d_in[7];
  const int*   jj      = (const int*)d_in[8];
  float* out = (float*)d_out;

  char* ws = (char*)d_ws;
  float* partial     = (float*)ws;                               // 544 f32
  unsigned short* xb = (unsigned short*)(ws + 8192);             // 8192*64 bf16 = 1 MB
  float* sq          = (float*)(ws + 8192 + 1048576);            // 8192 f32
  float* denomS      = (float*)(ws + 8192 + 1048576 + 32768);    // 8192 f32

  row_engine<<<256, 256, 0, stream>>>(logits, noise_f, noise_i, noise_j,
                                      topic_w, tb, ii, jj, xb, sq, denomS);
  pairwise<<<NPAIR_BLOCKS, 256, 0, stream>>>(xb, sq, partial);
  finalize<<<32, 256, 0, stream>>>(pij, denomS, partial, out);
}